// Round 4
// baseline (45.994 us; speedup 1.0000x reference)
//
#include <hip/hip_runtime.h>
#include <hip/hip_bf16.h>
#include <hip/hip_fp16.h>

typedef int      i32x4 __attribute__((ext_vector_type(4)));
typedef unsigned u32x4 __attribute__((ext_vector_type(4)));
typedef float    f32x2 __attribute__((ext_vector_type(2)));
typedef float    f32x4 __attribute__((ext_vector_type(4)));

// Phase 1: convert h (fp32, [N,16]) -> fp16 table in workspace (32 B/row).
// 3.2 MB fits per-XCD L2. Source read is nontemporal (pure streaming).
__global__ __launch_bounds__(256) void convert_h_fp16(
    const f32x4* __restrict__ h4,    // [N*4]
    uint4* __restrict__ hh,          // [N*2] uint4 (8 halfs each)
    int n_out)                       // N*2
{
    int i = blockIdx.x * blockDim.x + threadIdx.x;
    if (i >= n_out) return;
    f32x4 a = __builtin_nontemporal_load(h4 + 2 * i);
    f32x4 b = __builtin_nontemporal_load(h4 + 2 * i + 1);
    __half2 p[4];
    p[0] = __floats2half2_rn(a.x, a.y);
    p[1] = __floats2half2_rn(a.z, a.w);
    p[2] = __floats2half2_rn(b.x, b.y);
    p[3] = __floats2half2_rn(b.z, b.w);
    hh[i] = *reinterpret_cast<const uint4*>(p);   // table: NORMAL store (want it cached)
}

__device__ __forceinline__ float dot2u(unsigned a, unsigned b) {
    __half2 ha = *reinterpret_cast<const __half2*>(&a);
    __half2 hb = *reinterpret_cast<const __half2*>(&b);
    float2 fa = __half22float2(ha);
    float2 fb = __half22float2(hb);
    return fa.x * fb.x + fa.y * fb.y;
}

__device__ __forceinline__ float dot8u(uint4 a, uint4 b) {
    return dot2u(a.x, b.x) + dot2u(a.y, b.y) + dot2u(a.z, b.z) + dot2u(a.w, b.w);
}

__device__ __forceinline__ float dot16(const uint4* __restrict__ hh, int s, int d) {
    uint4 a0 = hh[(size_t)s * 2];
    uint4 a1 = hh[(size_t)s * 2 + 1];
    uint4 b0 = hh[(size_t)d * 2];
    uint4 b1 = hh[(size_t)d * 2 + 1];
    return dot8u(a0, b0) + dot8u(a1, b1);
}

// Phase 2: lane-pair per edge group of 8. Lanes 2i/2i+1 each own one 16B half
// of every 32B row (same 64B line -> coalesced). All streaming accesses
// (indices in, results out) are NONTEMPORAL so they don't evict the 3.2 MB
// table from the per-XCD L2; table gathers are normal loads (L2-resident).
__global__ __launch_bounds__(256) void edge_dot_pair(
    const uint4* __restrict__ hh,    // [N*2] (row = 2 x uint4)
    const i32x4* __restrict__ src4,  // [E/4]
    const i32x4* __restrict__ dst4,  // [E/4]
    f32x2* __restrict__ out2,        // [E/2]
    int ng,                          // E/8 (groups of 8 edges)
    const int* __restrict__ src,     // scalar views for tail
    const int* __restrict__ dst,
    float* __restrict__ out,
    int E)
{
    int tid = blockIdx.x * blockDim.x + threadIdx.x;
    int half = tid & 1;              // which 16B half of each row this lane owns
    int pair = tid >> 1;
    int pstride = (gridDim.x * blockDim.x) >> 1;

    for (int g = pair; g < ng; g += pstride) {
        i32x4 sa = __builtin_nontemporal_load(src4 + 2 * g);
        i32x4 sb = __builtin_nontemporal_load(src4 + 2 * g + 1);
        i32x4 da = __builtin_nontemporal_load(dst4 + 2 * g);
        i32x4 db = __builtin_nontemporal_load(dst4 + 2 * g + 1);
        int ss[8] = {sa.x, sa.y, sa.z, sa.w, sb.x, sb.y, sb.z, sb.w};
        int dd[8] = {da.x, da.y, da.z, da.w, db.x, db.y, db.z, db.w};
        float r[8];
#pragma unroll
        for (int k = 0; k < 8; ++k) {
            uint4 a = hh[(size_t)ss[k] * 2 + half];
            uint4 b = hh[(size_t)dd[k] * 2 + half];
            float partial = dot8u(a, b);
            r[k] = partial + __shfl_xor(partial, 1, 64);
        }
        // Pair stores 8 results as four adjacent f32x2 (each pair-instruction
        // covers 16B contiguous), nontemporal.
        f32x2 v0, v1;
        if (half == 0) { v0.x = r[0]; v0.y = r[1]; v1.x = r[4]; v1.y = r[5]; }
        else           { v0.x = r[2]; v0.y = r[3]; v1.x = r[6]; v1.y = r[7]; }
        __builtin_nontemporal_store(v0, out2 + (size_t)g * 4 + half);
        __builtin_nontemporal_store(v1, out2 + (size_t)g * 4 + 2 + half);
    }

    // tail (E % 8 != 0)
    if (tid == 0) {
        for (int e = ng * 8; e < E; ++e)
            out[e] = dot16(hh, src[e], dst[e]);
    }
}

// Fallback (ws too small): fp32 gather kernel.
__global__ __launch_bounds__(256) void edge_dot_fp32(
    const float4* __restrict__ h,
    const int* __restrict__ src,
    const int* __restrict__ dst,
    float* __restrict__ out,
    int E)
{
    int idx = blockIdx.x * blockDim.x + threadIdx.x;
    int stride = gridDim.x * blockDim.x;
    for (int e = idx; e < E; e += stride) {
        int s = src[e];
        int d = dst[e];
        const float4* hs = h + (size_t)s * 4;
        const float4* hd = h + (size_t)d * 4;
        float acc = 0.0f;
#pragma unroll
        for (int k = 0; k < 4; ++k) {
            float4 a = hs[k];
            float4 b = hd[k];
            acc += a.x * b.x + a.y * b.y + a.z * b.z + a.w * b.w;
        }
        out[e] = acc;
    }
}

extern "C" void kernel_launch(void* const* d_in, const int* in_sizes, int n_in,
                              void* d_out, int out_size, void* d_ws, size_t ws_size,
                              hipStream_t stream) {
    const float* h   = (const float*)d_in[0];   // [N, 16] fp32
    const int*   src = (const int*)d_in[1];     // [E] int32
    const int*   dst = (const int*)d_in[2];     // [E]
    float*       out = (float*)d_out;           // [E]

    const int N = in_sizes[0] / 16;
    const int E = in_sizes[1];

    const size_t need = (size_t)N * 16 * sizeof(__half);  // 3.2 MB
    if (ws_size >= need && E >= 8) {
        uint4* hh = (uint4*)d_ws;
        int n_out = N * 2;
        convert_h_fp16<<<(n_out + 255) / 256, 256, 0, stream>>>(
            (const f32x4*)h, hh, n_out);

        int ng = E / 8;
        long long threads = (long long)ng * 2;
        int grid = (int)((threads + 255) / 256);
        if (grid < 1) grid = 1;
        edge_dot_pair<<<grid, 256, 0, stream>>>(
            (const uint4*)hh, (const i32x4*)src, (const i32x4*)dst, (f32x2*)out,
            ng, src, dst, out, E);
    } else {
        int grid = (E + 255) / 256;
        if (grid > 2048) grid = 2048;
        edge_dot_fp32<<<grid, 256, 0, stream>>>(
            (const float4*)h, src, dst, out, E);
    }
}